// Round 7
// baseline (403.098 us; speedup 1.0000x reference)
//
#include <hip/hip_runtime.h>
#include <hip/hip_bf16.h>
#include <cstdint>

#define SEQ 4096
#define NB 4
#define DIM 1024
#define MTOT (NB * SEQ)   // 16384
constexpr size_t EL = (size_t)MTOT * DIM;

using u16x8  = __attribute__((ext_vector_type(8))) unsigned short;
using bf16x8 = __attribute__((ext_vector_type(8))) __bf16;
using f32x4  = __attribute__((ext_vector_type(4))) float;

__device__ __forceinline__ unsigned short f2bf(float f) {
  return __builtin_bit_cast(unsigned short, __float2bfloat16(f));  // native RNE cvt
}

__device__ __forceinline__ void gload16(const unsigned short* g, unsigned short* l) {
  __builtin_amdgcn_global_load_lds(
      (const __attribute__((address_space(1))) unsigned int*)g,
      (__attribute__((address_space(3))) unsigned int*)l, 16, 0, 0);
}
__device__ __forceinline__ void stage_half(const unsigned short* gsrc, size_t ld,
                                           unsigned short* ldst) {
  gload16(gsrc, ldst);
  gload16(gsrc + 64 * ld, ldst + 64 * 64);
}

#define BAR()   __builtin_amdgcn_s_barrier()
#define FENCE() asm volatile("" ::: "memory")

// ------- prep: x fp32->bf16, bias concat, lsum zero (one dispatch) -------
__global__ __launch_bounds__(256) void prep(const float* __restrict__ x,
                                            unsigned short* __restrict__ xb,
                                            const float* __restrict__ bq,
                                            const float* __restrict__ bk,
                                            const float* __restrict__ bv,
                                            float* __restrict__ bc,
                                            float* __restrict__ l) {
  const size_t gid = (size_t)blockIdx.x * 256 + threadIdx.x;
  const size_t i = gid * 4;
  float4 v = *(const float4*)(x + i);
  ushort4 o;
  o.x = f2bf(v.x); o.y = f2bf(v.y); o.z = f2bf(v.z); o.w = f2bf(v.w);
  *(ushort4*)(xb + i) = o;
  if (gid < MTOT) l[gid] = 0.f;
  if (gid < 3 * DIM)
    bc[gid] = gid < DIM ? bq[gid] : gid < 2 * DIM ? bk[gid - DIM] : bv[gid - 2 * DIM];
}

// ------- W fp32 [1024][1024] -> WT bf16, 3 matrices via blockIdx.z -------
__global__ __launch_bounds__(256) void transpose_w3(const float* __restrict__ Wq,
                                                    const float* __restrict__ Wk,
                                                    const float* __restrict__ Wv,
                                                    unsigned short* __restrict__ WT) {
  const float* W = blockIdx.z == 0 ? Wq : blockIdx.z == 1 ? Wk : Wv;
  unsigned short* O = WT + (size_t)blockIdx.z * DIM * DIM;
  __shared__ float tile[32][33];
  const int tx = threadIdx.x, ty = threadIdx.y;
  const int d0 = blockIdx.y * 32, e0 = blockIdx.x * 32;
#pragma unroll
  for (int j = 0; j < 32; j += 8)
    tile[ty + j][tx] = W[(size_t)(d0 + ty + j) * DIM + e0 + tx];
  __syncthreads();
#pragma unroll
  for (int j = 0; j < 32; j += 8)
    O[(size_t)(e0 + ty + j) * DIM + d0 + tx] = f2bf(tile[tx][ty + j]);
}

// ============ 256x256 8-phase BT-GEMM body: C[M,N] = A[M,K] * B^T ============
// 512 thr = 8 waves (2M x 4N); wave tile 128x64; BK=64; LDS 128KiB (2 K-tile bufs).
// ds_reads software-pipelined ONE PHASE AHEAD of their consuming MFMA phase:
//   b1@P1 -> M2, a1@P2 -> M3, next-tile {a0,b0}@P4(after vmcnt) -> M1'.
enum { EPI_QKV = 0, EPI_EXP = 1, EPI_PV = 2 };

template <int EPI>
__device__ __forceinline__ void gemm_body(
    const unsigned short* __restrict__ A, const unsigned short* __restrict__ B,
    void* __restrict__ C, const float* __restrict__ bias, float* __restrict__ lsum,
    int K, int lda, int ldb, int ldc, float scale,
    int row0, int col0, int bz, long sA, long sB, long sC) {
  __shared__ unsigned short sm[2][2][256 * 64];   // 128 KiB
  const int t    = threadIdx.x;
  const int lane = t & 63;
  const int wave = t >> 6;
  const int wm   = wave >> 2;          // 0..1  (M half)
  const int wn   = wave & 3;           // 0..3  (N quarter)
  const int fr   = lane & 15;
  const int g    = lane >> 4;          // k-group
  const int xr   = (fr & 7) << 4;      // read-side XOR

  const unsigned short* Ab = A + (size_t)bz * (size_t)sA;
  const unsigned short* Bb = B + (size_t)bz * (size_t)sB;

  const int srow = t >> 3;
  const int scol = ((((t & 7) << 4) ^ ((srow & 7) << 4)) >> 1);
  const unsigned short* gA = Ab + (size_t)(row0 + srow) * (size_t)lda + scol;
  const unsigned short* gB = Bb + (size_t)(col0 + srow) * (size_t)ldb + scol;

  const int arow = wm * 128 + fr;
  const int brow = wn * 64 + fr;
  const int c0 = (((g << 4)) ^ xr) >> 1;
  const int c1 = ((64 | (g << 4)) ^ xr) >> 1;

  f32x4 acc[8][4];
  const f32x4 z4 = {0.f, 0.f, 0.f, 0.f};
#pragma unroll
  for (int i = 0; i < 8; ++i)
#pragma unroll
    for (int j = 0; j < 4; ++j) acc[i][j] = z4;

  const int nt = K >> 6;

  stage_half(gA, lda, &sm[0][0][wave * 512]);
  stage_half(gA + 128 * (size_t)lda, lda, &sm[0][0][8192 + wave * 512]);
  stage_half(gB, ldb, &sm[0][1][wave * 512]);
  stage_half(gB + 128 * (size_t)ldb, ldb, &sm[0][1][8192 + wave * 512]);
  if (nt > 1) {
    stage_half(gB + 64, ldb, &sm[1][1][wave * 512]);
    stage_half(gB + 128 * (size_t)ldb + 64, ldb, &sm[1][1][8192 + wave * 512]);
    stage_half(gA + 64, lda, &sm[1][0][wave * 512]);
    asm volatile("s_waitcnt vmcnt(6)" ::: "memory");   // T0's 8 loads landed
  } else {
    asm volatile("s_waitcnt vmcnt(0)" ::: "memory");
  }
  BAR(); FENCE();

  bf16x8 a0[4][2], a1[4][2], b0[2][2], b1[2][2];

  // initial reads for tile 0 (a0, b0) — consumed by M1 of kt=0
  {
    const unsigned short* As  = sm[0][0];
    const unsigned short* Bs2 = sm[0][1];
#pragma unroll
    for (int mi = 0; mi < 4; ++mi) {
      a0[mi][0] = *(const bf16x8*)(As + (arow + mi * 16) * 64 + c0);
      a0[mi][1] = *(const bf16x8*)(As + (arow + mi * 16) * 64 + c1);
    }
#pragma unroll
    for (int ni = 0; ni < 2; ++ni) {
      b0[ni][0] = *(const bf16x8*)(Bs2 + (brow + ni * 16) * 64 + c0);
      b0[ni][1] = *(const bf16x8*)(Bs2 + (brow + ni * 16) * 64 + c1);
    }
  }

  for (int kt = 0; kt < nt; ++kt) {
    const int p = kt & 1;
    const unsigned short* As  = sm[p][0];
    const unsigned short* Bs2 = sm[p][1];
    const unsigned short* Asn = sm[p ^ 1][0];
    const unsigned short* Bsn = sm[p ^ 1][1];

    // ---- P1: stage T(kt+1).A-hi; read b1 (-> M2); MFMA q1 (a0 x b0) ----
    if (kt + 1 < nt)
      stage_half(gA + 128 * (size_t)lda + (size_t)(kt + 1) * 64, lda,
                 &sm[p ^ 1][0][8192 + wave * 512]);
    FENCE(); BAR(); FENCE();
#pragma unroll
    for (int ni = 0; ni < 2; ++ni) {
      b1[ni][0] = *(const bf16x8*)(Bs2 + (brow + (ni + 2) * 16) * 64 + c0);
      b1[ni][1] = *(const bf16x8*)(Bs2 + (brow + (ni + 2) * 16) * 64 + c1);
    }
    __builtin_amdgcn_s_setprio(1);
#pragma unroll
    for (int mi = 0; mi < 4; ++mi)
#pragma unroll
      for (int ni = 0; ni < 2; ++ni) {
        acc[mi][ni] = __builtin_amdgcn_mfma_f32_16x16x32_bf16(a0[mi][0], b0[ni][0], acc[mi][ni], 0, 0, 0);
        acc[mi][ni] = __builtin_amdgcn_mfma_f32_16x16x32_bf16(a0[mi][1], b0[ni][1], acc[mi][ni], 0, 0, 0);
      }
    __builtin_amdgcn_s_setprio(0);
    FENCE(); BAR(); FENCE();

    // ---- P2: read a1 (-> M3); MFMA q2 (a0 x b1) ----
#pragma unroll
    for (int mi = 0; mi < 4; ++mi) {
      a1[mi][0] = *(const bf16x8*)(As + (arow + (mi + 4) * 16) * 64 + c0);
      a1[mi][1] = *(const bf16x8*)(As + (arow + (mi + 4) * 16) * 64 + c1);
    }
    FENCE(); BAR(); FENCE();
    __builtin_amdgcn_s_setprio(1);
#pragma unroll
    for (int mi = 0; mi < 4; ++mi)
#pragma unroll
      for (int ni = 0; ni < 2; ++ni) {
        acc[mi][ni + 2] = __builtin_amdgcn_mfma_f32_16x16x32_bf16(a0[mi][0], b1[ni][0], acc[mi][ni + 2], 0, 0, 0);
        acc[mi][ni + 2] = __builtin_amdgcn_mfma_f32_16x16x32_bf16(a0[mi][1], b1[ni][1], acc[mi][ni + 2], 0, 0, 0);
      }
    __builtin_amdgcn_s_setprio(0);
    FENCE(); BAR(); FENCE();

    // ---- P3: stage T(kt+2).B-lo; MFMA q3 (a1 x b0) ----
    if (kt + 2 < nt)
      stage_half(gB + (size_t)(kt + 2) * 64, ldb, &sm[p][1][wave * 512]);
    FENCE(); BAR(); FENCE();
    __builtin_amdgcn_s_setprio(1);
#pragma unroll
    for (int mi = 0; mi < 4; ++mi)
#pragma unroll
      for (int ni = 0; ni < 2; ++ni) {
        acc[mi + 4][ni] = __builtin_amdgcn_mfma_f32_16x16x32_bf16(a1[mi][0], b0[ni][0], acc[mi + 4][ni], 0, 0, 0);
        acc[mi + 4][ni] = __builtin_amdgcn_mfma_f32_16x16x32_bf16(a1[mi][1], b0[ni][1], acc[mi + 4][ni], 0, 0, 0);
      }
    __builtin_amdgcn_s_setprio(0);
    FENCE(); BAR(); FENCE();

    // ---- P4: stage T(kt+2).{B-hi,A-lo}; counted vmcnt; read next {a0,b0}; MFMA q4 ----
    if (kt + 2 < nt) {
      stage_half(gB + 128 * (size_t)ldb + (size_t)(kt + 2) * 64, ldb,
                 &sm[p][1][8192 + wave * 512]);
      stage_half(gA + (size_t)(kt + 2) * 64, lda, &sm[p][0][wave * 512]);
      // 6 newest outstanding = T(kt+2) stages -> waits until T(kt+1) fully landed
      asm volatile("s_waitcnt vmcnt(6)" ::: "memory");
    } else {
      asm volatile("s_waitcnt vmcnt(0)" ::: "memory");
    }
    if (kt + 1 < nt) {
#pragma unroll
      for (int mi = 0; mi < 4; ++mi) {
        a0[mi][0] = *(const bf16x8*)(Asn + (arow + mi * 16) * 64 + c0);
        a0[mi][1] = *(const bf16x8*)(Asn + (arow + mi * 16) * 64 + c1);
      }
#pragma unroll
      for (int ni = 0; ni < 2; ++ni) {
        b0[ni][0] = *(const bf16x8*)(Bsn + (brow + ni * 16) * 64 + c0);
        b0[ni][1] = *(const bf16x8*)(Bsn + (brow + ni * 16) * 64 + c1);
      }
    }
    FENCE(); BAR(); FENCE();
    __builtin_amdgcn_s_setprio(1);
#pragma unroll
    for (int mi = 0; mi < 4; ++mi)
#pragma unroll
      for (int ni = 0; ni < 2; ++ni) {
        acc[mi + 4][ni + 2] = __builtin_amdgcn_mfma_f32_16x16x32_bf16(a1[mi][0], b1[ni][0], acc[mi + 4][ni + 2], 0, 0, 0);
        acc[mi + 4][ni + 2] = __builtin_amdgcn_mfma_f32_16x16x32_bf16(a1[mi][1], b1[ni][1], acc[mi + 4][ni + 2], 0, 0, 0);
      }
    __builtin_amdgcn_s_setprio(0);
    FENCE(); BAR(); FENCE();
  }

  // ===================== LDS-staged coalesced epilogues =====================
  char* Lb = (char*)&sm[0][0][0];
  const int rb = (lane >> 4) * 4;

  if constexpr (EPI == EPI_QKV) {
    const int which = col0 >> 10;            // 0=Q 1=K 2=V
    const int lc0   = col0 & 1023;
    unsigned short* Co = (unsigned short*)C + (size_t)which * EL;
    if (which < 2) {
      float bb[4];
#pragma unroll
      for (int ni = 0; ni < 4; ++ni) bb[ni] = bias[col0 + wn * 64 + ni * 16 + fr];
#pragma unroll
      for (int mi = 0; mi < 8; ++mi) {
        const int r0 = wm * 128 + mi * 16 + rb;
#pragma unroll
        for (int ni = 0; ni < 4; ++ni) {
          const int c = wn * 64 + ni * 16 + fr;
#pragma unroll
          for (int j = 0; j < 4; ++j) {
            const int r = r0 + j;
            *(unsigned short*)(Lb + r * 512 + ((c * 2) ^ ((r & 7) << 4))) =
                f2bf(acc[mi][ni][j] + bb[ni]);
          }
        }
      }
      __syncthreads();
#pragma unroll 4
      for (int i = 0; i < 16; ++i) {
        const int G = i * 512 + t;
        const int r = G >> 5, c16 = G & 31;
        u16x8 v = *(const u16x8*)(Lb + r * 512 + ((c16 * 16) ^ ((r & 7) << 4)));
        *(u16x8*)(Co + (size_t)(row0 + r) * DIM + lc0 + c16 * 8) = v;
      }
    } else {
      // V: store transposed through col-major LDS tile
#pragma unroll
      for (int ni = 0; ni < 4; ++ni) {
        const int c = wn * 64 + ni * 16 + fr;
        const float bb = bias[col0 + c];
#pragma unroll
        for (int mi = 0; mi < 8; ++mi) {
          const int r0 = wm * 128 + mi * 16 + rb;
          ushort4 pk;
          pk.x = f2bf(acc[mi][ni][0] + bb);
          pk.y = f2bf(acc[mi][ni][1] + bb);
          pk.z = f2bf(acc[mi][ni][2] + bb);
          pk.w = f2bf(acc[mi][ni][3] + bb);
          *(ushort4*)(Lb + c * 512 + ((r0 * 2) ^ ((c & 7) << 4))) = pk;
        }
      }
      __syncthreads();
      unsigned short* Cv = Co;
#pragma unroll 4
      for (int i = 0; i < 16; ++i) {
        const int G = i * 512 + t;
        const int e = G >> 5, m16 = G & 31;
        u16x8 v = *(const u16x8*)(Lb + e * 512 + ((m16 * 16) ^ ((e & 7) << 4)));
        *(u16x8*)(Cv + (size_t)(lc0 + e) * MTOT + row0 + m16 * 8) = v;
      }
    }
  } else if constexpr (EPI == EPI_EXP) {
    // E = exp2(acc*scale); row sums reduced from registers (shfl), then
    // coalesced E store through LDS.
#pragma unroll
    for (int mi = 0; mi < 8; ++mi)
#pragma unroll
      for (int ni = 0; ni < 4; ++ni)
#pragma unroll
        for (int j = 0; j < 4; ++j)
          acc[mi][ni][j] = exp2f(acc[mi][ni][j] * scale);

#pragma unroll
    for (int mi = 0; mi < 8; ++mi)
#pragma unroll
      for (int j = 0; j < 4; ++j) {
        float s = acc[mi][0][j] + acc[mi][1][j] + acc[mi][2][j] + acc[mi][3][j];
        s += __shfl_xor(s, 1);
        s += __shfl_xor(s, 2);
        s += __shfl_xor(s, 4);
        s += __shfl_xor(s, 8);
        if (fr == 0)
          atomicAdd(&lsum[(size_t)bz * SEQ + row0 + wm * 128 + mi * 16 + rb + j], s);
      }

#pragma unroll
    for (int mi = 0; mi < 8; ++mi) {
      const int r0 = wm * 128 + mi * 16 + rb;
#pragma unroll
      for (int ni = 0; ni < 4; ++ni) {
        const int c = wn * 64 + ni * 16 + fr;
#pragma unroll
        for (int j = 0; j < 4; ++j) {
          const int r = r0 + j;
          *(unsigned short*)(Lb + r * 512 + ((c * 2) ^ ((r & 7) << 4))) =
              f2bf(acc[mi][ni][j]);
        }
      }
    }
    __syncthreads();
    unsigned short* Co = (unsigned short*)C + (size_t)bz * (size_t)sC;
#pragma unroll 4
    for (int i = 0; i < 16; ++i) {
      const int G = i * 512 + t;
      const int r = G >> 5, c16 = G & 31;
      u16x8 v = *(const u16x8*)(Lb + r * 512 + ((c16 * 16) ^ ((r & 7) << 4)));
      *(u16x8*)(Co + (size_t)(row0 + r) * (size_t)ldc + col0 + c16 * 8) = v;
    }
  } else {  // EPI_PV: fp32 out / lsum[row], two 128-row halves through LDS
    float* Co = (float*)C + (size_t)bz * (size_t)sC;
#pragma unroll
    for (int h = 0; h < 2; ++h) {
      if (h) __syncthreads();
      if (wm == h) {
#pragma unroll
        for (int mi = 0; mi < 8; ++mi) {
          const int r0 = mi * 16 + rb;
#pragma unroll
          for (int ni = 0; ni < 4; ++ni) {
            const int c = wn * 64 + ni * 16 + fr;
#pragma unroll
            for (int j = 0; j < 4; ++j) {
              const int r = r0 + j;
              *(float*)(Lb + r * 1024 + ((c * 4) ^ ((r & 7) << 4))) = acc[mi][ni][j];
            }
          }
        }
      }
      __syncthreads();
#pragma unroll 4
      for (int i = 0; i < 16; ++i) {
        const int G = i * 512 + t;
        const int r = G >> 6, c4 = G & 63;
        f32x4 v = *(const f32x4*)(Lb + r * 1024 + ((c4 * 16) ^ ((r & 7) << 4)));
        const size_t grow = (size_t)row0 + h * 128 + r;
        const float inv = 1.0f / lsum[(size_t)bz * SEQ + grow];
        v *= inv;
        *(f32x4*)(Co + grow * (size_t)ldc + col0 + c4 * 4) = v;
      }
    }
  }
}

// ---------------- named wrappers (distinct rocprof attribution) ----------------
__global__ __launch_bounds__(512, 2) void gemm_qkv(
    const unsigned short* __restrict__ A, const unsigned short* __restrict__ B,
    unsigned short* __restrict__ C, const float* __restrict__ bcat) {
  gemm_body<EPI_QKV>(A, B, C, bcat, nullptr, DIM, DIM, DIM, DIM, 1.f,
                     (int)blockIdx.x * 256, (int)blockIdx.y * 256, 0, 0, 0, 0);
}

__global__ __launch_bounds__(512, 2) void gemm_exp(
    const unsigned short* __restrict__ A, const unsigned short* __restrict__ B,
    unsigned short* __restrict__ C, float* __restrict__ lsum) {
  // E = exp2(S * log2e/32); scale folds 1/sqrt(1024) and log2(e)
  gemm_body<EPI_EXP>(A, B, C, nullptr, lsum, DIM, DIM, DIM, SEQ, 0.04508422f,
                     (int)blockIdx.x * 256, (int)blockIdx.y * 256, (int)blockIdx.z,
                     (long)SEQ * DIM, (long)SEQ * DIM, (long)SEQ * SEQ);
}

__global__ __launch_bounds__(512, 2) void gemm_pv(
    const unsigned short* __restrict__ A, const unsigned short* __restrict__ B,
    float* __restrict__ C, float* __restrict__ lsum) {
  // grid (4,16,NB) flat-swizzled so each XCD gets 8 row-tiles x 4 col-tiles
  const int flat = (int)blockIdx.x +
                   (int)gridDim.x * ((int)blockIdx.y + (int)gridDim.y * (int)blockIdx.z);
  const int nf  = (flat & 7) * 32 + (flat >> 3);   // 256 = 8 XCD x 32, bijective
  const int b   = nf >> 6;
  const int rc  = nf & 63;
  const int row = rc >> 2, col = rc & 3;
  gemm_body<EPI_PV>(A, B, C, nullptr, lsum, SEQ, SEQ, MTOT, DIM, 1.f,
                    row * 256, col * 256, b,
                    (long)SEQ * SEQ, (long)SEQ, (long)SEQ * DIM);
}

extern "C" void kernel_launch(void* const* d_in, const int* in_sizes, int n_in,
                              void* d_out, int out_size, void* d_ws, size_t ws_size,
                              hipStream_t stream) {
  (void)in_sizes; (void)n_in; (void)out_size; (void)ws_size;
  const float* x  = (const float*)d_in[0];
  const float* Wq = (const float*)d_in[1];
  const float* bq = (const float*)d_in[2];
  const float* Wk = (const float*)d_in[3];
  const float* bk = (const float*)d_in[4];
  const float* Wv = (const float*)d_in[5];
  const float* bv = (const float*)d_in[6];
  float* out = (float*)d_out;

  const size_t SALL = (size_t)NB * SEQ * SEQ;
  unsigned short* Q  = (unsigned short*)d_ws;
  unsigned short* Km = Q + EL;
  unsigned short* VT = Km + EL;                  // transposed: VT[e][b*SEQ+s]
  unsigned short* Sb = VT + EL;                  // E = exp(S/32), unnormalized
  unsigned short* WT = Sb + SALL;                // [3072][1024] = WqT|WkT|WvT
  float*          l  = (float*)(WT + (size_t)3 * DIM * DIM);   // [MTOT] row sums
  float*          bc = l + MTOT;                 // bcat[3072]
  unsigned short* xb = Sb;                       // x_bf16 overlaps E (dead after proj)

  prep<<<dim3(EL / 1024), dim3(256), 0, stream>>>(x, xb, bq, bk, bv, bc, l);
  transpose_w3<<<dim3(32, 32, 3), dim3(32, 8), 0, stream>>>(Wq, Wk, Wv, WT);

  // fused QKV projection: [16384,1024] x [3072,1024]^T, epilogue routes Q/K/VT
  gemm_qkv<<<dim3(MTOT / 256, 3 * DIM / 256), 512, 0, stream>>>(xb, WT, Q, bc);

  // E = exp(QK^T/32) (bf16) + row sums l (register shfl reduce + atomics)
  gemm_exp<<<dim3(SEQ / 256, SEQ / 256, NB), 512, 0, stream>>>(Q, Km, Sb, l);

  // O = (E · V) / l  (fp32 out), XCD-swizzled grid
  gemm_pv<<<dim3(DIM / 256, SEQ / 256, NB), 512, 0, stream>>>(Sb, VT, out, l);
}

// Round 8
// 401.496 us; speedup vs baseline: 1.0040x; 1.0040x over previous
//
#include <hip/hip_runtime.h>
#include <hip/hip_bf16.h>
#include <cstdint>

#define SEQ 4096
#define NB 4
#define DIM 1024
#define MTOT (NB * SEQ)   // 16384
constexpr size_t EL = (size_t)MTOT * DIM;

using u16x8  = __attribute__((ext_vector_type(8))) unsigned short;
using bf16x8 = __attribute__((ext_vector_type(8))) __bf16;
using f32x4  = __attribute__((ext_vector_type(4))) float;

__device__ __forceinline__ unsigned short f2bf(float f) {
  return __builtin_bit_cast(unsigned short, __float2bfloat16(f));  // native RNE cvt
}

__device__ __forceinline__ void gload16(const unsigned short* g, unsigned short* l) {
  __builtin_amdgcn_global_load_lds(
      (const __attribute__((address_space(1))) unsigned int*)g,
      (__attribute__((address_space(3))) unsigned int*)l, 16, 0, 0);
}
__device__ __forceinline__ void stage_half(const unsigned short* gsrc, size_t ld,
                                           unsigned short* ldst) {
  gload16(gsrc, ldst);
  gload16(gsrc + 64 * ld, ldst + 64 * 64);
}

#define BAR()   __builtin_amdgcn_s_barrier()
#define FENCE() asm volatile("" ::: "memory")

// ------- prep: x fp32->bf16, bias concat, lsum zero (one dispatch) -------
__global__ __launch_bounds__(256) void prep(const float* __restrict__ x,
                                            unsigned short* __restrict__ xb,
                                            const float* __restrict__ bq,
                                            const float* __restrict__ bk,
                                            const float* __restrict__ bv,
                                            float* __restrict__ bc,
                                            float* __restrict__ l) {
  const size_t gid = (size_t)blockIdx.x * 256 + threadIdx.x;
  const size_t i = gid * 4;
  float4 v = *(const float4*)(x + i);
  ushort4 o;
  o.x = f2bf(v.x); o.y = f2bf(v.y); o.z = f2bf(v.z); o.w = f2bf(v.w);
  *(ushort4*)(xb + i) = o;
  if (gid < MTOT) l[gid] = 0.f;
  if (gid < 3 * DIM)
    bc[gid] = gid < DIM ? bq[gid] : gid < 2 * DIM ? bk[gid - DIM] : bv[gid - 2 * DIM];
}

// ------- W fp32 [1024][1024] -> WT bf16, 3 matrices via blockIdx.z -------
__global__ __launch_bounds__(256) void transpose_w3(const float* __restrict__ Wq,
                                                    const float* __restrict__ Wk,
                                                    const float* __restrict__ Wv,
                                                    unsigned short* __restrict__ WT) {
  const float* W = blockIdx.z == 0 ? Wq : blockIdx.z == 1 ? Wk : Wv;
  unsigned short* O = WT + (size_t)blockIdx.z * DIM * DIM;
  __shared__ float tile[32][33];
  const int tx = threadIdx.x, ty = threadIdx.y;
  const int d0 = blockIdx.y * 32, e0 = blockIdx.x * 32;
#pragma unroll
  for (int j = 0; j < 32; j += 8)
    tile[ty + j][tx] = W[(size_t)(d0 + ty + j) * DIM + e0 + tx];
  __syncthreads();
#pragma unroll
  for (int j = 0; j < 32; j += 8)
    O[(size_t)(e0 + ty + j) * DIM + d0 + tx] = f2bf(tile[tx][ty + j]);
}

// ============ 256x256 8-phase BT-GEMM body: C[M,N] = A[M,K] * B^T ============
// 512 thr = 8 waves (2M x 4N); wave tile 128x64; BK=64; LDS 128KiB (2 K-tile bufs).
// Race-free R6 schedule: each phase's ds_reads issued before the phase barrier,
// consumed after it; next-tile reads happen at NEXT iteration's P1 (all waves'
// vmcnt(6) synchronized by the P4 closing barrier).
enum { EPI_QKV = 0, EPI_EXP = 1, EPI_PV = 2 };

template <int EPI>
__device__ __forceinline__ void gemm_body(
    const unsigned short* __restrict__ A, const unsigned short* __restrict__ B,
    void* __restrict__ C, const float* __restrict__ bias, float* __restrict__ lsum,
    int K, int lda, int ldb, int ldc, float scale,
    int row0, int col0, int bz, long sA, long sB, long sC) {
  __shared__ unsigned short sm[2][2][256 * 64];   // 128 KiB
  const int t    = threadIdx.x;
  const int lane = t & 63;
  const int wave = t >> 6;
  const int wm   = wave >> 2;          // 0..1  (M half)
  const int wn   = wave & 3;           // 0..3  (N quarter)
  const int fr   = lane & 15;
  const int g    = lane >> 4;          // k-group
  const int xr   = (fr & 7) << 4;      // read-side XOR

  const unsigned short* Ab = A + (size_t)bz * (size_t)sA;
  const unsigned short* Bb = B + (size_t)bz * (size_t)sB;

  const int srow = t >> 3;
  const int scol = ((((t & 7) << 4) ^ ((srow & 7) << 4)) >> 1);
  const unsigned short* gA = Ab + (size_t)(row0 + srow) * (size_t)lda + scol;
  const unsigned short* gB = Bb + (size_t)(col0 + srow) * (size_t)ldb + scol;

  const int arow = wm * 128 + fr;
  const int brow = wn * 64 + fr;
  const int c0 = (((g << 4)) ^ xr) >> 1;
  const int c1 = ((64 | (g << 4)) ^ xr) >> 1;

  f32x4 acc[8][4];
  const f32x4 z4 = {0.f, 0.f, 0.f, 0.f};
#pragma unroll
  for (int i = 0; i < 8; ++i)
#pragma unroll
    for (int j = 0; j < 4; ++j) acc[i][j] = z4;

  const int nt = K >> 6;

  stage_half(gA, lda, &sm[0][0][wave * 512]);
  stage_half(gA + 128 * (size_t)lda, lda, &sm[0][0][8192 + wave * 512]);
  stage_half(gB, ldb, &sm[0][1][wave * 512]);
  stage_half(gB + 128 * (size_t)ldb, ldb, &sm[0][1][8192 + wave * 512]);
  if (nt > 1) {
    stage_half(gB + 64, ldb, &sm[1][1][wave * 512]);
    stage_half(gB + 128 * (size_t)ldb + 64, ldb, &sm[1][1][8192 + wave * 512]);
    stage_half(gA + 64, lda, &sm[1][0][wave * 512]);
    asm volatile("s_waitcnt vmcnt(6)" ::: "memory");
  } else {
    asm volatile("s_waitcnt vmcnt(0)" ::: "memory");
  }
  BAR(); FENCE();

  bf16x8 a0[4][2], a1[4][2], b0[2][2], b1[2][2];

  for (int kt = 0; kt < nt; ++kt) {
    const int p = kt & 1;
    const unsigned short* As  = sm[p][0];
    const unsigned short* Bs2 = sm[p][1];

    // P1: read A0-3 + B0-1 (12), stage T(kt+1).A-hi
#pragma unroll
    for (int mi = 0; mi < 4; ++mi) {
      a0[mi][0] = *(const bf16x8*)(As + (arow + mi * 16) * 64 + c0);
      a0[mi][1] = *(const bf16x8*)(As + (arow + mi * 16) * 64 + c1);
    }
#pragma unroll
    for (int ni = 0; ni < 2; ++ni) {
      b0[ni][0] = *(const bf16x8*)(Bs2 + (brow + ni * 16) * 64 + c0);
      b0[ni][1] = *(const bf16x8*)(Bs2 + (brow + ni * 16) * 64 + c1);
    }
    if (kt + 1 < nt)
      stage_half(gA + 128 * (size_t)lda + (size_t)(kt + 1) * 64, lda,
                 &sm[p ^ 1][0][8192 + wave * 512]);
    FENCE(); BAR(); FENCE();
    __builtin_amdgcn_s_setprio(1);
#pragma unroll
    for (int mi = 0; mi < 4; ++mi)
#pragma unroll
      for (int ni = 0; ni < 2; ++ni) {
        acc[mi][ni] = __builtin_amdgcn_mfma_f32_16x16x32_bf16(a0[mi][0], b0[ni][0], acc[mi][ni], 0, 0, 0);
        acc[mi][ni] = __builtin_amdgcn_mfma_f32_16x16x32_bf16(a0[mi][1], b0[ni][1], acc[mi][ni], 0, 0, 0);
      }
    __builtin_amdgcn_s_setprio(0);
    FENCE(); BAR(); FENCE();

    // P2: read B2-3 (4)
#pragma unroll
    for (int ni = 0; ni < 2; ++ni) {
      b1[ni][0] = *(const bf16x8*)(Bs2 + (brow + (ni + 2) * 16) * 64 + c0);
      b1[ni][1] = *(const bf16x8*)(Bs2 + (brow + (ni + 2) * 16) * 64 + c1);
    }
    FENCE(); BAR(); FENCE();
    __builtin_amdgcn_s_setprio(1);
#pragma unroll
    for (int mi = 0; mi < 4; ++mi)
#pragma unroll
      for (int ni = 0; ni < 2; ++ni) {
        acc[mi][ni + 2] = __builtin_amdgcn_mfma_f32_16x16x32_bf16(a0[mi][0], b1[ni][0], acc[mi][ni + 2], 0, 0, 0);
        acc[mi][ni + 2] = __builtin_amdgcn_mfma_f32_16x16x32_bf16(a0[mi][1], b1[ni][1], acc[mi][ni + 2], 0, 0, 0);
      }
    __builtin_amdgcn_s_setprio(0);
    FENCE(); BAR(); FENCE();

    // P3: read A4-7 (8), stage T(kt+2).B-lo
#pragma unroll
    for (int mi = 0; mi < 4; ++mi) {
      a1[mi][0] = *(const bf16x8*)(As + (arow + (mi + 4) * 16) * 64 + c0);
      a1[mi][1] = *(const bf16x8*)(As + (arow + (mi + 4) * 16) * 64 + c1);
    }
    if (kt + 2 < nt)
      stage_half(gB + (size_t)(kt + 2) * 64, ldb, &sm[p][1][wave * 512]);
    FENCE(); BAR(); FENCE();
    __builtin_amdgcn_s_setprio(1);
#pragma unroll
    for (int mi = 0; mi < 4; ++mi)
#pragma unroll
      for (int ni = 0; ni < 2; ++ni) {
        acc[mi + 4][ni] = __builtin_amdgcn_mfma_f32_16x16x32_bf16(a1[mi][0], b0[ni][0], acc[mi + 4][ni], 0, 0, 0);
        acc[mi + 4][ni] = __builtin_amdgcn_mfma_f32_16x16x32_bf16(a1[mi][1], b0[ni][1], acc[mi + 4][ni], 0, 0, 0);
      }
    __builtin_amdgcn_s_setprio(0);
    FENCE(); BAR(); FENCE();

    // P4: stage T(kt+2).{B-hi,A-lo}; counted vmcnt; MFMA q4
    if (kt + 2 < nt) {
      stage_half(gB + 128 * (size_t)ldb + (size_t)(kt + 2) * 64, ldb,
                 &sm[p][1][8192 + wave * 512]);
      stage_half(gA + (size_t)(kt + 2) * 64, lda, &sm[p][0][wave * 512]);
      asm volatile("s_waitcnt vmcnt(6)" ::: "memory");
    } else {
      asm volatile("s_waitcnt vmcnt(0)" ::: "memory");
    }
    FENCE(); BAR(); FENCE();
    __builtin_amdgcn_s_setprio(1);
#pragma unroll
    for (int mi = 0; mi < 4; ++mi)
#pragma unroll
      for (int ni = 0; ni < 2; ++ni) {
        acc[mi + 4][ni + 2] = __builtin_amdgcn_mfma_f32_16x16x32_bf16(a1[mi][0], b1[ni][0], acc[mi + 4][ni + 2], 0, 0, 0);
        acc[mi + 4][ni + 2] = __builtin_amdgcn_mfma_f32_16x16x32_bf16(a1[mi][1], b1[ni][1], acc[mi + 4][ni + 2], 0, 0, 0);
      }
    __builtin_amdgcn_s_setprio(0);
    FENCE(); BAR(); FENCE();
  }

  // ===================== LDS-staged coalesced epilogues =====================
  char* Lb = (char*)&sm[0][0][0];
  const int rb = (lane >> 4) * 4;

  if constexpr (EPI == EPI_QKV) {
    const int which = col0 >> 10;            // 0=Q 1=K 2=V
    const int lc0   = col0 & 1023;
    unsigned short* Co = (unsigned short*)C + (size_t)which * EL;
    if (which < 2) {
      float bb[4];
#pragma unroll
      for (int ni = 0; ni < 4; ++ni) bb[ni] = bias[col0 + wn * 64 + ni * 16 + fr];
#pragma unroll
      for (int mi = 0; mi < 8; ++mi) {
        const int r0 = wm * 128 + mi * 16 + rb;
#pragma unroll
        for (int ni = 0; ni < 4; ++ni) {
          const int c = wn * 64 + ni * 16 + fr;
#pragma unroll
          for (int j = 0; j < 4; ++j) {
            const int r = r0 + j;
            *(unsigned short*)(Lb + r * 512 + ((c * 2) ^ ((r & 7) << 4))) =
                f2bf(acc[mi][ni][j] + bb[ni]);
          }
        }
      }
      __syncthreads();
#pragma unroll 4
      for (int i = 0; i < 16; ++i) {
        const int G = i * 512 + t;
        const int r = G >> 5, c16 = G & 31;
        u16x8 v = *(const u16x8*)(Lb + r * 512 + ((c16 * 16) ^ ((r & 7) << 4)));
        *(u16x8*)(Co + (size_t)(row0 + r) * DIM + lc0 + c16 * 8) = v;
      }
    } else {
      // V: store transposed through col-major LDS tile
#pragma unroll
      for (int ni = 0; ni < 4; ++ni) {
        const int c = wn * 64 + ni * 16 + fr;
        const float bb = bias[col0 + c];
#pragma unroll
        for (int mi = 0; mi < 8; ++mi) {
          const int r0 = wm * 128 + mi * 16 + rb;
          ushort4 pk;
          pk.x = f2bf(acc[mi][ni][0] + bb);
          pk.y = f2bf(acc[mi][ni][1] + bb);
          pk.z = f2bf(acc[mi][ni][2] + bb);
          pk.w = f2bf(acc[mi][ni][3] + bb);
          *(ushort4*)(Lb + c * 512 + ((r0 * 2) ^ ((c & 7) << 4))) = pk;
        }
      }
      __syncthreads();
#pragma unroll 4
      for (int i = 0; i < 16; ++i) {
        const int G = i * 512 + t;
        const int e = G >> 5, m16 = G & 31;
        u16x8 v = *(const u16x8*)(Lb + e * 512 + ((m16 * 16) ^ ((e & 7) << 4)));
        *(u16x8*)(Co + (size_t)(lc0 + e) * MTOT + row0 + m16 * 8) = v;
      }
    }
  } else if constexpr (EPI == EPI_EXP) {
    // E = exp2(acc*scale); row sums reduced from registers (shfl), then
    // coalesced E store through LDS.
#pragma unroll
    for (int mi = 0; mi < 8; ++mi)
#pragma unroll
      for (int ni = 0; ni < 4; ++ni)
#pragma unroll
        for (int j = 0; j < 4; ++j)
          acc[mi][ni][j] = exp2f(acc[mi][ni][j] * scale);

#pragma unroll
    for (int mi = 0; mi < 8; ++mi)
#pragma unroll
      for (int j = 0; j < 4; ++j) {
        float s = acc[mi][0][j] + acc[mi][1][j] + acc[mi][2][j] + acc[mi][3][j];
        s += __shfl_xor(s, 1);
        s += __shfl_xor(s, 2);
        s += __shfl_xor(s, 4);
        s += __shfl_xor(s, 8);
        if (fr == 0)
          atomicAdd(&lsum[(size_t)bz * SEQ + row0 + wm * 128 + mi * 16 + rb + j], s);
      }

#pragma unroll
    for (int mi = 0; mi < 8; ++mi) {
      const int r0 = wm * 128 + mi * 16 + rb;
#pragma unroll
      for (int ni = 0; ni < 4; ++ni) {
        const int c = wn * 64 + ni * 16 + fr;
#pragma unroll
        for (int j = 0; j < 4; ++j) {
          const int r = r0 + j;
          *(unsigned short*)(Lb + r * 512 + ((c * 2) ^ ((r & 7) << 4))) =
              f2bf(acc[mi][ni][j]);
        }
      }
    }
    __syncthreads();
    unsigned short* Co = (unsigned short*)C + (size_t)bz * (size_t)sC;
#pragma unroll 4
    for (int i = 0; i < 16; ++i) {
      const int G = i * 512 + t;
      const int r = G >> 5, c16 = G & 31;
      u16x8 v = *(const u16x8*)(Lb + r * 512 + ((c16 * 16) ^ ((r & 7) << 4)));
      *(u16x8*)(Co + (size_t)(row0 + r) * (size_t)ldc + col0 + c16 * 8) = v;
    }
  } else {  // EPI_PV: fp32 out / lsum[row], two 128-row halves through LDS
    float* Co = (float*)C + (size_t)bz * (size_t)sC;
#pragma unroll
    for (int h = 0; h < 2; ++h) {
      if (h) __syncthreads();
      if (wm == h) {
#pragma unroll
        for (int mi = 0; mi < 8; ++mi) {
          const int r0 = mi * 16 + rb;
#pragma unroll
          for (int ni = 0; ni < 4; ++ni) {
            const int c = wn * 64 + ni * 16 + fr;
#pragma unroll
            for (int j = 0; j < 4; ++j) {
              const int r = r0 + j;
              *(float*)(Lb + r * 1024 + ((c * 4) ^ ((r & 7) << 4))) = acc[mi][ni][j];
            }
          }
        }
      }
      __syncthreads();
#pragma unroll 4
      for (int i = 0; i < 16; ++i) {
        const int G = i * 512 + t;
        const int r = G >> 6, c4 = G & 63;
        f32x4 v = *(const f32x4*)(Lb + r * 1024 + ((c4 * 16) ^ ((r & 7) << 4)));
        const size_t grow = (size_t)row0 + h * 128 + r;
        const float inv = 1.0f / lsum[(size_t)bz * SEQ + grow];
        v *= inv;
        *(f32x4*)(Co + grow * (size_t)ldc + col0 + c4 * 4) = v;
      }
    }
  }
}

// ---------------- named wrappers with XCD-locality block remaps ----------------
// Assumption (perf-only): dispatch assigns blockIdx flat order round-robin to
// XCDs, i.e. xcd = flat & 7 (guide §1/m157).

__global__ __launch_bounds__(512, 2) void gemm_qkv(
    const unsigned short* __restrict__ A, const unsigned short* __restrict__ B,
    unsigned short* __restrict__ C, const float* __restrict__ bcat) {
  // 768 blocks. XCD x owns x-row band of 8 row-tiles (4 MB, L2-resident),
  // sweeps 12 W-columns; co-resident set = 8 rows x 4 cols = 6 MB then steady.
  const int flat = (int)blockIdx.x + 64 * (int)blockIdx.y;   // 0..767
  const int xcd = flat & 7, j = flat >> 3;                   // j 0..95
  const int row = xcd * 8 + (j & 7);                         // 0..63
  const int col = j >> 3;                                    // 0..11
  gemm_body<EPI_QKV>(A, B, C, bcat, nullptr, DIM, DIM, DIM, DIM, 1.f,
                     row * 256, col * 256, 0, 0, 0, 0);
}

__global__ __launch_bounds__(512, 2) void gemm_exp(
    const unsigned short* __restrict__ A, const unsigned short* __restrict__ B,
    unsigned short* __restrict__ C, float* __restrict__ lsum) {
  // 1024 blocks. XCD x owns Q-row band (x&3)*4..+3 (2 MB resident) for batches
  // {0,1} (x<4) or {2,3} (x>=4); sweeps 16 K-columns per batch.
  const int flat = (int)blockIdx.x +
                   (int)gridDim.x * ((int)blockIdx.y + (int)gridDim.y * (int)blockIdx.z);
  const int xcd = flat & 7, j = flat >> 3;   // j 0..127
  const int bz  = (xcd >> 2) * 2 + (j >> 6); // 0..3
  const int jj  = j & 63;
  const int row = (xcd & 3) * 4 + (jj & 3);  // 0..15
  const int col = jj >> 2;                   // 0..15
  gemm_body<EPI_EXP>(A, B, C, nullptr, lsum, DIM, DIM, DIM, SEQ, 0.04508422f,
                     row * 256, col * 256, bz,
                     (long)SEQ * DIM, (long)SEQ * DIM, (long)SEQ * SEQ);
}

__global__ __launch_bounds__(512, 2) void gemm_pv(
    const unsigned short* __restrict__ A, const unsigned short* __restrict__ B,
    float* __restrict__ C, float* __restrict__ lsum) {
  // grid (4,16,NB) flat-swizzled so each XCD gets 8 row-tiles x 4 col-tiles
  const int flat = (int)blockIdx.x +
                   (int)gridDim.x * ((int)blockIdx.y + (int)gridDim.y * (int)blockIdx.z);
  const int nf  = (flat & 7) * 32 + (flat >> 3);   // 256 = 8 XCD x 32, bijective
  const int b   = nf >> 6;
  const int rc  = nf & 63;
  const int row = rc >> 2, col = rc & 3;
  gemm_body<EPI_PV>(A, B, C, nullptr, lsum, SEQ, SEQ, MTOT, DIM, 1.f,
                    row * 256, col * 256, b,
                    (long)SEQ * SEQ, (long)SEQ, (long)SEQ * DIM);
}

extern "C" void kernel_launch(void* const* d_in, const int* in_sizes, int n_in,
                              void* d_out, int out_size, void* d_ws, size_t ws_size,
                              hipStream_t stream) {
  (void)in_sizes; (void)n_in; (void)out_size; (void)ws_size;
  const float* x  = (const float*)d_in[0];
  const float* Wq = (const float*)d_in[1];
  const float* bq = (const float*)d_in[2];
  const float* Wk = (const float*)d_in[3];
  const float* bk = (const float*)d_in[4];
  const float* Wv = (const float*)d_in[5];
  const float* bv = (const float*)d_in[6];
  float* out = (float*)d_out;

  const size_t SALL = (size_t)NB * SEQ * SEQ;
  unsigned short* Q  = (unsigned short*)d_ws;
  unsigned short* Km = Q + EL;
  unsigned short* VT = Km + EL;                  // transposed: VT[e][b*SEQ+s]
  unsigned short* Sb = VT + EL;                  // E = exp(S/32), unnormalized
  unsigned short* WT = Sb + SALL;                // [3072][1024] = WqT|WkT|WvT
  float*          l  = (float*)(WT + (size_t)3 * DIM * DIM);   // [MTOT] row sums
  float*          bc = l + MTOT;                 // bcat[3072]
  unsigned short* xb = Sb;                       // x_bf16 overlaps E (dead after proj)

  prep<<<dim3(EL / 1024), dim3(256), 0, stream>>>(x, xb, bq, bk, bv, bc, l);
  transpose_w3<<<dim3(32, 32, 3), dim3(32, 8), 0, stream>>>(Wq, Wk, Wv, WT);

  // fused QKV projection: [16384,1024] x [3072,1024]^T, epilogue routes Q/K/VT
  gemm_qkv<<<dim3(64, 12), 512, 0, stream>>>(xb, WT, Q, bc);

  // E = exp(QK^T/32) (bf16) + row sums l (register shfl reduce + atomics)
  gemm_exp<<<dim3(SEQ / 256, SEQ / 256, NB), 512, 0, stream>>>(Q, Km, Sb, l);

  // O = (E · V) / l  (fp32 out), XCD-swizzled grid
  gemm_pv<<<dim3(DIM / 256, SEQ / 256, NB), 512, 0, stream>>>(Sb, VT, out, l);
}